// Round 15
// baseline (56.106 us; speedup 1.0000x reference)
//
#include <hip/hip_runtime.h>
#include <math.h>

// Problem constants (from reference)
#define B_    64
#define C_    8
#define T_    2048
#define K_    16
#define NF_   9
#define FEAT_ 144   // C_*NF_*2
#define MLP_  16
#define H1_   64
#define H2_   32
#define EFF_  60
#define W_    1988  // T_-EFF_
#define NCHK_ 16    // w-chunks of 128 (2 w per thread)
#define PI_F  3.14159265358979323846f
// LDS padded strides (floats): 4 sub-groups hit disjoint bank quads (mod-32 verified)
#define SPW   36
#define S1    20
#define S2    36

// ---- packed fp32 FMA via inline asm: acc += a*b per 32-bit half ----
typedef float v2f __attribute__((ext_vector_type(2)));
__device__ __forceinline__ void pkfma(v2f& acc, v2f a, v2f b) {
  asm("v_pk_fma_f32 %0, %1, %2, %0" : "+v"(acc) : "v"(a), "v"(b));
}
__device__ __forceinline__ v2f mkv2(float x, float y) { v2f r; r.x = x; r.y = y; return r; }
__device__ __forceinline__ v2f lo2(float4 a) { return mkv2(a.x, a.y); }
__device__ __forceinline__ v2f hi2(float4 a) { return mkv2(a.z, a.w); }

// Twiddles: angle(t) = 2*pi*t/16; f[n] = sum win[k]*exp(-i*2*pi*n*k/16)
constexpr float COS16[16] = {
   1.0f,  0.92387953251128674f,  0.70710678118654752f,  0.38268343236508977f,
   0.0f, -0.38268343236508977f, -0.70710678118654752f, -0.92387953251128674f,
  -1.0f, -0.92387953251128674f, -0.70710678118654752f, -0.38268343236508977f,
   0.0f,  0.38268343236508977f,  0.70710678118654752f,  0.92387953251128674f };
constexpr float SIN16F[16] = {
   0.0f,  0.38268343236508977f,  0.70710678118654752f,  0.92387953251128674f,
   1.0f,  0.92387953251128674f,  0.70710678118654752f,  0.38268343236508977f,
   0.0f, -0.38268343236508977f, -0.70710678118654752f, -0.92387953251128674f,
  -1.0f, -0.92387953251128674f, -0.70710678118654752f, -0.38268343236508977f };

// ---- fast device math (hw transcendentals) ----
__device__ __forceinline__ float fast_log1p(float s) {
  return __builtin_amdgcn_logf(1.0f + s) * 0.69314718055994531f;
}
__device__ __forceinline__ float atanpi_poly(float r) {
  const float s2 = r * r;
  float p = -0.0037310f;
  p = fmaf(p, s2,  0.0167600f);
  p = fmaf(p, s2, -0.0370617f);
  p = fmaf(p, s2,  0.0616068f);
  p = fmaf(p, s2, -0.10587734f);
  p = fmaf(p, s2,  0.31830265f);
  return r * p;
}
__device__ __forceinline__ float atan2pi_fast(float im, float re) {
  const float ax = fabsf(re), ay = fabsf(im);
  const float mx = fmaxf(ax, ay), mn = fminf(ax, ay);
  const float r = mn * __builtin_amdgcn_rcpf(fmaxf(mx, 1e-37f));
  float t = atanpi_poly(r);
  t = (ay > ax) ? 0.5f - t : t;
  t = (__float_as_uint(re) & 0x80000000u) ? 1.0f - t : t;  // signbit(re), handles -0
  return copysignf(t, im);                                  // im=+0 keeps +pi convention
}
__device__ __forceinline__ float fast_tanh(float z) {
  const float az = fabsf(z);
  const float e = __builtin_amdgcn_exp2f(-2.8853900817779268f * az);  // exp(-2|z|)
  const float th = fmaf(-2.0f, e * __builtin_amdgcn_rcpf(1.0f + e), 1.0f);
  return copysignf(th, z);
}

// ---------------- Kernel 0: fused setup (softmax + weight transposes) ----------------
__global__ __launch_bounds__(256) void setup_kernel(const float* __restrict__ agg,
                                                    float* __restrict__ wts,
                                                    const float* __restrict__ pw,
                                                    const float* __restrict__ w2,
                                                    float* __restrict__ PWt,
                                                    float* __restrict__ W2t) {
  if (blockIdx.x == 0) {
    __shared__ float red[256];
    const int tid = threadIdx.x;
    float m = -INFINITY;
    for (int i = tid; i < W_; i += 256) m = fmaxf(m, agg[i]);
    red[tid] = m; __syncthreads();
    for (int s = 128; s > 0; s >>= 1) { if (tid < s) red[tid] = fmaxf(red[tid], red[tid+s]); __syncthreads(); }
    const float mx = red[0];
    __syncthreads();
    float sum = 0.f;
    for (int i = tid; i < W_; i += 256) sum += expf(agg[i] - mx);
    red[tid] = sum; __syncthreads();
    for (int s = 128; s > 0; s >>= 1) { if (tid < s) red[tid] += red[tid+s]; __syncthreads(); }
    const float inv = 1.f / red[0];
    for (int i = tid; i < W_; i += 256) wts[i] = expf(agg[i] - mx) * inv;
  } else {
    const int tid = (blockIdx.x - 1) * 256 + threadIdx.x;
    if (tid < MLP_ * FEAT_) {
      const int j = tid / FEAT_, f = tid - j * FEAT_;  // pw[j][f]
      PWt[f * MLP_ + j] = pw[tid];                     // [144][16]: rows pair (mag,ph)
    }
    if (tid < H2_ * H1_) {
      const int m = tid >> 6, i = tid & 63;            // w2[m][i]
      W2t[i * H2_ + m] = w2[tid];
    }
  }
}

// ---------------- Kernel 1: R14 structure, channel loop NOT unrolled (I-cache test) ----------------
// lane = (sub<<4)|wloc; sub handles channels {2sub,2sub+1}, MLP rows i≡sub (mod 4).
// Each thread computes w and w+64 sharing one LDS weight-read stream. Single change vs
// R14: #pragma unroll 1 on the cc loop -> code size ~-35% (testing instruction-fetch limit).
__global__ __launch_bounds__(256) void tcn_fused(
    const float* __restrict__ x,
    const float* __restrict__ PWt, const float* __restrict__ proj_b,
    const float* __restrict__ w1, const float* __restrict__ b1,
    const float* __restrict__ W2t, const float* __restrict__ b2,
    const float* __restrict__ out_w, const float* __restrict__ out_b,
    const float* __restrict__ wts, float* __restrict__ partials) {
  __shared__ __align__(16) float PWl[72 * SPW];   // row r=c*9+n: [mag16 | ph16]
  __shared__ __align__(16) float W1p[H1_ * S1];
  __shared__ __align__(16) float W2p[H1_ * S2];
  __shared__ float B1s[H1_];

  const int tid = threadIdx.x;
  for (int idx = tid; idx < 72 * 32; idx += 256) { const int r = idx >> 5, j = idx & 31; PWl[r * SPW + j] = PWt[idx]; }
  for (int idx = tid; idx < H1_ * MLP_; idx += 256) { const int i = idx >> 4, j = idx & 15; W1p[i * S1 + j] = w1[idx]; }
  for (int idx = tid; idx < H1_ * H2_; idx += 256) { const int i = idx >> 5, m = idx & 31; W2p[i * S2 + m] = W2t[idx]; }
  if (tid < H1_) B1s[tid] = b1[tid];
  __syncthreads();   // the only barrier in the body

  const int lane = tid & 63;
  const int wave = tid >> 6;
  const int wloc = lane & 15;
  const int sub  = lane >> 4;
  const int b     = blockIdx.y;
  const int chunk = blockIdx.x;
  const int wA = chunk * 128 + wave * 16 + wloc;   // max 1983 < W_: always valid
  const int wB = wA + 64;
  const int wBl = (wB < W_) ? wB : (W_ - 1);       // clamp loads; mask at the end

  // ---- DFT + feature + proj partials for channels 2sub, 2sub+1; both w's share weight reads ----
  v2f paccA[8], paccB[8];
  #pragma unroll
  for (int q = 0; q < 8; q++) { paccA[q] = mkv2(0.f, 0.f); paccB[q] = mkv2(0.f, 0.f); }

  #pragma unroll 1
  for (int cc = 0; cc < 2; cc++) {
    const int c = sub * 2 + cc;
    const float* xrow = x + ((size_t)b * C_ + c) * T_;
    const float* xcA = xrow + wA;
    const float* xcB = xrow + wBl;
    float winA[K_], winB[K_];
    #pragma unroll
    for (int k = 0; k < K_; k++) { winA[k] = xcA[k * 4]; winB[k] = xcB[k * 4]; }
    float aeA[8], boA[8], aeB[8], boB[8];
    #pragma unroll
    for (int k = 0; k < 8; k++) {
      aeA[k] = winA[k] + winA[k+8]; boA[k] = winA[k] - winA[k+8];
      aeB[k] = winB[k] + winB[k+8]; boB[k] = winB[k] - winB[k+8];
    }

    // n = 0, 8: im == +0 exactly -> mag = log1p(|re|), ph = signbit(re)
    {
      const float r0A = ((aeA[0]+aeA[1])+(aeA[2]+aeA[3]))+((aeA[4]+aeA[5])+(aeA[6]+aeA[7]));
      const float r8A = ((aeA[0]-aeA[1])+(aeA[2]-aeA[3]))+((aeA[4]-aeA[5])+(aeA[6]-aeA[7]));
      const float r0B = ((aeB[0]+aeB[1])+(aeB[2]+aeB[3]))+((aeB[4]+aeB[5])+(aeB[6]+aeB[7]));
      const float r8B = ((aeB[0]-aeB[1])+(aeB[2]-aeB[3]))+((aeB[4]-aeB[5])+(aeB[6]-aeB[7]));
      const float m0A = fast_log1p(fabsf(r0A)), m8A = fast_log1p(fabsf(r8A));
      const float m0B = fast_log1p(fabsf(r0B)), m8B = fast_log1p(fabsf(r8B));
      const float p0A = (__float_as_uint(r0A) >> 31) ? 1.f : 0.f;
      const float p8A = (__float_as_uint(r8A) >> 31) ? 1.f : 0.f;
      const float p0B = (__float_as_uint(r0B) >> 31) ? 1.f : 0.f;
      const float p8B = (__float_as_uint(r8B) >> 31) ? 1.f : 0.f;
      const v2f mm0A = mkv2(m0A, m0A), mm8A = mkv2(m8A, m8A);
      const v2f mm0B = mkv2(m0B, m0B), mm8B = mkv2(m8B, m8B);
      const v2f pp0A = mkv2(p0A, p0A), pp8A = mkv2(p8A, p8A);
      const v2f pp0B = mkv2(p0B, p0B), pp8B = mkv2(p8B, p8B);
      const float4* rv0 = reinterpret_cast<const float4*>(&PWl[(c * NF_ + 0) * SPW]);
      const float4* rv8 = reinterpret_cast<const float4*>(&PWl[(c * NF_ + 8) * SPW]);
      #pragma unroll
      for (int q = 0; q < 4; q++) {
        const float4 a0 = rv0[q], c0 = rv0[q + 4];   // one weight read serves A and B
        const float4 a8 = rv8[q], c8 = rv8[q + 4];
        pkfma(paccA[2*q],   mm0A, lo2(a0));  pkfma(paccA[2*q],   pp0A, lo2(c0));
        pkfma(paccA[2*q+1], mm0A, hi2(a0));  pkfma(paccA[2*q+1], pp0A, hi2(c0));
        pkfma(paccA[2*q],   mm8A, lo2(a8));  pkfma(paccA[2*q],   pp8A, lo2(c8));
        pkfma(paccA[2*q+1], mm8A, hi2(a8));  pkfma(paccA[2*q+1], pp8A, hi2(c8));
        pkfma(paccB[2*q],   mm0B, lo2(a0));  pkfma(paccB[2*q],   pp0B, lo2(c0));
        pkfma(paccB[2*q+1], mm0B, hi2(a0));  pkfma(paccB[2*q+1], pp0B, hi2(c0));
        pkfma(paccB[2*q],   mm8B, lo2(a8));  pkfma(paccB[2*q],   pp8B, lo2(c8));
        pkfma(paccB[2*q+1], mm8B, hi2(a8));  pkfma(paccB[2*q+1], pp8B, hi2(c8));
      }
    }

    // n = 1..7: full twiddles, A and B interleaved, weights read once
    #pragma unroll
    for (int n = 1; n < 8; n++) {
      float reA = 0.f, imA = 0.f, reB = 0.f, imB = 0.f;
      #pragma unroll
      for (int k = 0; k < 8; k++) {
        const int t = (n * k) & 15;
        const float cv = COS16[t], sv = -SIN16F[t];
        const float vA = (n & 1) ? boA[k] : aeA[k];
        const float vB = (n & 1) ? boB[k] : aeB[k];
        reA = fmaf(vA, cv, reA); imA = fmaf(vA, sv, imA);
        reB = fmaf(vB, cv, reB); imB = fmaf(vB, sv, imB);
      }
      const float sA = __builtin_amdgcn_sqrtf(fmaf(reA, reA, imA * imA));
      const float sB = __builtin_amdgcn_sqrtf(fmaf(reB, reB, imB * imB));
      const float magA = fast_log1p(sA), magB = fast_log1p(sB);
      const float phA = atan2pi_fast(imA, reA), phB = atan2pi_fast(imB, reB);
      const v2f mmA = mkv2(magA, magA), ppA = mkv2(phA, phA);
      const v2f mmB = mkv2(magB, magB), ppB = mkv2(phB, phB);
      const float4* rmv = reinterpret_cast<const float4*>(&PWl[(c * NF_ + n) * SPW]);
      #pragma unroll
      for (int q = 0; q < 4; q++) {
        const float4 a  = rmv[q];       // mag weights (read once)
        const float4 bb = rmv[q + 4];   // ph weights
        pkfma(paccA[2*q],   mmA, lo2(a));  pkfma(paccA[2*q],   ppA, lo2(bb));
        pkfma(paccA[2*q+1], mmA, hi2(a));  pkfma(paccA[2*q+1], ppA, hi2(bb));
        pkfma(paccB[2*q],   mmB, lo2(a));  pkfma(paccB[2*q],   ppB, lo2(bb));
        pkfma(paccB[2*q+1], mmB, hi2(a));  pkfma(paccB[2*q+1], ppB, hi2(bb));
      }
    }
  }

  // ---- combine pacc across subs (proven shfl_xor butterflies) ----
  float* pfA = reinterpret_cast<float*>(paccA);
  float* pfB = reinterpret_cast<float*>(paccB);
  #pragma unroll
  for (int j = 0; j < MLP_; j++) {
    pfA[j] += __shfl_xor(pfA[j], 16, 64);
    pfA[j] += __shfl_xor(pfA[j], 32, 64);
    pfB[j] += __shfl_xor(pfB[j], 16, 64);
    pfB[j] += __shfl_xor(pfB[j], 32, 64);
  }
  v2f p2A[8], p2B[8];
  #pragma unroll
  for (int q = 0; q < 8; q++) {
    p2A[q] = mkv2(fast_tanh(pfA[2*q]   + proj_b[2*q])   * PI_F,
                  fast_tanh(pfA[2*q+1] + proj_b[2*q+1]) * PI_F);
    p2B[q] = mkv2(fast_tanh(pfB[2*q]   + proj_b[2*q])   * PI_F,
                  fast_tanh(pfB[2*q+1] + proj_b[2*q+1]) * PI_F);
  }

  // ---- MLP tail: 16 rows per sub; weight reads serve both w's ----
  v2f h2aA[16], h2aB[16];
  #pragma unroll
  for (int q = 0; q < 16; q++) { h2aA[q] = mkv2(0.f, 0.f); h2aB[q] = mkv2(0.f, 0.f); }
  #pragma unroll 4
  for (int ii = 0; ii < 16; ii++) {
    const int i = sub + ii * 4;
    const float4* r1 = reinterpret_cast<const float4*>(&W1p[i * S1]);
    v2f accA = mkv2(B1s[i], 0.f), accB = mkv2(B1s[i], 0.f);
    #pragma unroll
    for (int q = 0; q < 4; q++) {
      const float4 a = r1[q];
      pkfma(accA, p2A[2*q],   lo2(a));
      pkfma(accA, p2A[2*q+1], hi2(a));
      pkfma(accB, p2B[2*q],   lo2(a));
      pkfma(accB, p2B[2*q+1], hi2(a));
    }
    const float h1A = fmaxf(accA.x + accA.y, 0.f);
    const float h1B = fmaxf(accB.x + accB.y, 0.f);
    const v2f hhA = mkv2(h1A, h1A), hhB = mkv2(h1B, h1B);
    const float4* r2 = reinterpret_cast<const float4*>(&W2p[i * S2]);
    #pragma unroll
    for (int q = 0; q < 8; q++) {
      const float4 a = r2[q];
      pkfma(h2aA[2*q],   hhA, lo2(a));
      pkfma(h2aA[2*q+1], hhA, hi2(a));
      pkfma(h2aB[2*q],   hhB, lo2(a));
      pkfma(h2aB[2*q+1], hhB, hi2(a));
    }
  }
  // ---- combine h2a across subs ----
  float* hfA = reinterpret_cast<float*>(h2aA);
  float* hfB = reinterpret_cast<float*>(h2aB);
  #pragma unroll
  for (int m = 0; m < H2_; m++) {
    hfA[m] += __shfl_xor(hfA[m], 16, 64);
    hfA[m] += __shfl_xor(hfA[m], 32, 64);
    hfB[m] += __shfl_xor(hfB[m], 16, 64);
    hfB[m] += __shfl_xor(hfB[m], 32, 64);
  }

  // ---- head split across subs: m in [8*sub, 8*sub+8), combine ----
  float oA = 0.f, oB = 0.f;
  #pragma unroll
  for (int t = 0; t < 8; t++) {
    const int m = sub * 8 + t;
    const float bm = b2[m], wm = out_w[m];
    oA = fmaf(fmaxf(hfA[m] + bm, 0.f), wm, oA);
    oB = fmaf(fmaxf(hfB[m] + bm, 0.f), wm, oB);
  }
  oA += __shfl_xor(oA, 16, 64);
  oA += __shfl_xor(oA, 32, 64);
  oA += out_b[0];
  oB += __shfl_xor(oB, 16, 64);
  oB += __shfl_xor(oB, 32, 64);
  oB += out_b[0];

  float val = 0.f;
  if (sub == 0) {
    val = oA * wts[wA];
    if (wB < W_) val = fmaf(oB, wts[wB], val);
  }
  // reduce the 16 sub0 lanes (bits 0-3); other lanes mix garbage among themselves only
  #pragma unroll
  for (int s = 1; s < 16; s <<= 1) val += __shfl_xor(val, s, 64);
  if (lane == 0) partials[(b * NCHK_ + chunk) * 4 + wave] = val;
}

// ---------------- finalize: one wave per b, fixed-order butterfly over 64 partials ----------------
__global__ __launch_bounds__(64) void finalize_kernel(const float* __restrict__ partials,
                                                      float* __restrict__ out) {
  const int b = blockIdx.x;
  const int l = threadIdx.x;
  float s = partials[b * NCHK_ * 4 + l];   // NCHK_*4 = 64 values
  #pragma unroll
  for (int d = 1; d < 64; d <<= 1) s += __shfl_xor(s, d, 64);
  if (l == 0) out[b] = s;
}

extern "C" void kernel_launch(void* const* d_in, const int* in_sizes, int n_in,
                              void* d_out, int out_size, void* d_ws, size_t ws_size,
                              hipStream_t stream) {
  const float* x      = (const float*)d_in[0];
  const float* proj_w = (const float*)d_in[1];
  const float* proj_b = (const float*)d_in[2];
  const float* w1     = (const float*)d_in[3];
  const float* b1     = (const float*)d_in[4];
  const float* w2     = (const float*)d_in[5];
  const float* b2     = (const float*)d_in[6];
  const float* out_w  = (const float*)d_in[7];
  const float* out_b  = (const float*)d_in[8];
  const float* agg_w  = (const float*)d_in[9];

  float* wts      = (float*)d_ws;                    // 2048 floats
  float* PWt      = (float*)d_ws + 2048;             // 2304 floats
  float* W2t      = (float*)d_ws + 2048 + 2304;      // 2048 floats
  float* partials = (float*)d_ws + 8192;             // B_*NCHK_*4 = 4096 floats

  setup_kernel<<<10, 256, 0, stream>>>(agg_w, wts, proj_w, w2, PWt, W2t);
  tcn_fused<<<dim3(NCHK_, B_), 256, 0, stream>>>(x, PWt, proj_b, w1, b1, W2t, b2,
                                                 out_w, out_b, wts, partials);
  finalize_kernel<<<B_, 64, 0, stream>>>(partials, (float*)d_out);
}

// Round 16
// 53.937 us; speedup vs baseline: 1.0402x; 1.0402x over previous
//
#include <hip/hip_runtime.h>
#include <math.h>

// Problem constants (from reference)
#define B_    64
#define C_    8
#define T_    2048
#define K_    16
#define NF_   9
#define FEAT_ 144   // C_*NF_*2
#define MLP_  16
#define H1_   64
#define H2_   32
#define EFF_  60
#define W_    1988  // T_-EFF_
#define NCHK_ 16    // w-chunks of 128 (2 w per thread)
#define PI_F  3.14159265358979323846f
// LDS padded strides (floats): 4 sub-groups hit disjoint bank quads (mod-32 verified)
#define SPW   36
#define S1    20
#define S2    36

// ---- packed fp32 FMA via inline asm: acc += a*b per 32-bit half ----
typedef float v2f __attribute__((ext_vector_type(2)));
__device__ __forceinline__ void pkfma(v2f& acc, v2f a, v2f b) {
  asm("v_pk_fma_f32 %0, %1, %2, %0" : "+v"(acc) : "v"(a), "v"(b));
}
__device__ __forceinline__ v2f mkv2(float x, float y) { v2f r; r.x = x; r.y = y; return r; }
__device__ __forceinline__ v2f lo2(float4 a) { return mkv2(a.x, a.y); }
__device__ __forceinline__ v2f hi2(float4 a) { return mkv2(a.z, a.w); }

// Twiddles: angle(t) = 2*pi*t/16; f[n] = sum win[k]*exp(-i*2*pi*n*k/16)
constexpr float COS16[16] = {
   1.0f,  0.92387953251128674f,  0.70710678118654752f,  0.38268343236508977f,
   0.0f, -0.38268343236508977f, -0.70710678118654752f, -0.92387953251128674f,
  -1.0f, -0.92387953251128674f, -0.70710678118654752f, -0.38268343236508977f,
   0.0f,  0.38268343236508977f,  0.70710678118654752f,  0.92387953251128674f };
constexpr float SIN16F[16] = {
   0.0f,  0.38268343236508977f,  0.70710678118654752f,  0.92387953251128674f,
   1.0f,  0.92387953251128674f,  0.70710678118654752f,  0.38268343236508977f,
   0.0f, -0.38268343236508977f, -0.70710678118654752f, -0.92387953251128674f,
  -1.0f, -0.92387953251128674f, -0.70710678118654752f, -0.38268343236508977f };

// ---- fast device math (hw transcendentals) ----
__device__ __forceinline__ float fast_log1p(float s) {
  return __builtin_amdgcn_logf(1.0f + s) * 0.69314718055994531f;
}
__device__ __forceinline__ float atanpi_poly(float r) {
  const float s2 = r * r;
  float p = -0.0037310f;
  p = fmaf(p, s2,  0.0167600f);
  p = fmaf(p, s2, -0.0370617f);
  p = fmaf(p, s2,  0.0616068f);
  p = fmaf(p, s2, -0.10587734f);
  p = fmaf(p, s2,  0.31830265f);
  return r * p;
}
__device__ __forceinline__ float atan2pi_fast(float im, float re) {
  const float ax = fabsf(re), ay = fabsf(im);
  const float mx = fmaxf(ax, ay), mn = fminf(ax, ay);
  const float r = mn * __builtin_amdgcn_rcpf(fmaxf(mx, 1e-37f));
  float t = atanpi_poly(r);
  t = (ay > ax) ? 0.5f - t : t;
  t = (__float_as_uint(re) & 0x80000000u) ? 1.0f - t : t;  // signbit(re), handles -0
  return copysignf(t, im);                                  // im=+0 keeps +pi convention
}
__device__ __forceinline__ float fast_tanh(float z) {
  const float az = fabsf(z);
  const float e = __builtin_amdgcn_exp2f(-2.8853900817779268f * az);  // exp(-2|z|)
  const float th = fmaf(-2.0f, e * __builtin_amdgcn_rcpf(1.0f + e), 1.0f);
  return copysignf(th, z);
}

// ---------------- Kernel 0: fused setup (softmax + weight transposes) ----------------
__global__ __launch_bounds__(256) void setup_kernel(const float* __restrict__ agg,
                                                    float* __restrict__ wts,
                                                    const float* __restrict__ pw,
                                                    const float* __restrict__ w2,
                                                    float* __restrict__ PWt,
                                                    float* __restrict__ W2t) {
  if (blockIdx.x == 0) {
    __shared__ float red[256];
    const int tid = threadIdx.x;
    float m = -INFINITY;
    for (int i = tid; i < W_; i += 256) m = fmaxf(m, agg[i]);
    red[tid] = m; __syncthreads();
    for (int s = 128; s > 0; s >>= 1) { if (tid < s) red[tid] = fmaxf(red[tid], red[tid+s]); __syncthreads(); }
    const float mx = red[0];
    __syncthreads();
    float sum = 0.f;
    for (int i = tid; i < W_; i += 256) sum += expf(agg[i] - mx);
    red[tid] = sum; __syncthreads();
    for (int s = 128; s > 0; s >>= 1) { if (tid < s) red[tid] += red[tid+s]; __syncthreads(); }
    const float inv = 1.f / red[0];
    for (int i = tid; i < W_; i += 256) wts[i] = expf(agg[i] - mx) * inv;
  } else {
    const int tid = (blockIdx.x - 1) * 256 + threadIdx.x;
    if (tid < MLP_ * FEAT_) {
      const int j = tid / FEAT_, f = tid - j * FEAT_;  // pw[j][f]
      PWt[f * MLP_ + j] = pw[tid];                     // [144][16]: rows pair (mag,ph)
    }
    if (tid < H2_ * H1_) {
      const int m = tid >> 6, i = tid & 63;            // w2[m][i]
      W2t[i * H2_ + m] = w2[tid];
    }
  }
}

// ---------------- Kernel 1: 4 sub-lanes per w, 2 w per thread (weight-read amortized) ----------------
// lane = (sub<<4)|wloc; sub handles channels {2sub,2sub+1}, MLP rows i≡sub (mod 4).
// Each thread computes w and w+64 sharing one LDS weight-read stream. Best-measured
// configuration of the session (R14: 54.0 us total, tcn_fused 50.9 us).
__global__ __launch_bounds__(256) void tcn_fused(
    const float* __restrict__ x,
    const float* __restrict__ PWt, const float* __restrict__ proj_b,
    const float* __restrict__ w1, const float* __restrict__ b1,
    const float* __restrict__ W2t, const float* __restrict__ b2,
    const float* __restrict__ out_w, const float* __restrict__ out_b,
    const float* __restrict__ wts, float* __restrict__ partials) {
  __shared__ __align__(16) float PWl[72 * SPW];   // row r=c*9+n: [mag16 | ph16]
  __shared__ __align__(16) float W1p[H1_ * S1];
  __shared__ __align__(16) float W2p[H1_ * S2];
  __shared__ float B1s[H1_];

  const int tid = threadIdx.x;
  for (int idx = tid; idx < 72 * 32; idx += 256) { const int r = idx >> 5, j = idx & 31; PWl[r * SPW + j] = PWt[idx]; }
  for (int idx = tid; idx < H1_ * MLP_; idx += 256) { const int i = idx >> 4, j = idx & 15; W1p[i * S1 + j] = w1[idx]; }
  for (int idx = tid; idx < H1_ * H2_; idx += 256) { const int i = idx >> 5, m = idx & 31; W2p[i * S2 + m] = W2t[idx]; }
  if (tid < H1_) B1s[tid] = b1[tid];
  __syncthreads();   // the only barrier in the body

  const int lane = tid & 63;
  const int wave = tid >> 6;
  const int wloc = lane & 15;
  const int sub  = lane >> 4;
  const int b     = blockIdx.y;
  const int chunk = blockIdx.x;
  const int wA = chunk * 128 + wave * 16 + wloc;   // max 1983 < W_: always valid
  const int wB = wA + 64;
  const int wBl = (wB < W_) ? wB : (W_ - 1);       // clamp loads; mask at the end

  // ---- DFT + feature + proj partials for channels 2sub, 2sub+1; both w's share weight reads ----
  v2f paccA[8], paccB[8];
  #pragma unroll
  for (int q = 0; q < 8; q++) { paccA[q] = mkv2(0.f, 0.f); paccB[q] = mkv2(0.f, 0.f); }

  #pragma unroll
  for (int cc = 0; cc < 2; cc++) {
    const int c = sub * 2 + cc;
    const float* xrow = x + ((size_t)b * C_ + c) * T_;
    const float* xcA = xrow + wA;
    const float* xcB = xrow + wBl;
    float winA[K_], winB[K_];
    #pragma unroll
    for (int k = 0; k < K_; k++) { winA[k] = xcA[k * 4]; winB[k] = xcB[k * 4]; }
    float aeA[8], boA[8], aeB[8], boB[8];
    #pragma unroll
    for (int k = 0; k < 8; k++) {
      aeA[k] = winA[k] + winA[k+8]; boA[k] = winA[k] - winA[k+8];
      aeB[k] = winB[k] + winB[k+8]; boB[k] = winB[k] - winB[k+8];
    }

    // n = 0, 8: im == +0 exactly -> mag = log1p(|re|), ph = signbit(re)
    {
      const float r0A = ((aeA[0]+aeA[1])+(aeA[2]+aeA[3]))+((aeA[4]+aeA[5])+(aeA[6]+aeA[7]));
      const float r8A = ((aeA[0]-aeA[1])+(aeA[2]-aeA[3]))+((aeA[4]-aeA[5])+(aeA[6]-aeA[7]));
      const float r0B = ((aeB[0]+aeB[1])+(aeB[2]+aeB[3]))+((aeB[4]+aeB[5])+(aeB[6]+aeB[7]));
      const float r8B = ((aeB[0]-aeB[1])+(aeB[2]-aeB[3]))+((aeB[4]-aeB[5])+(aeB[6]-aeB[7]));
      const float m0A = fast_log1p(fabsf(r0A)), m8A = fast_log1p(fabsf(r8A));
      const float m0B = fast_log1p(fabsf(r0B)), m8B = fast_log1p(fabsf(r8B));
      const float p0A = (__float_as_uint(r0A) >> 31) ? 1.f : 0.f;
      const float p8A = (__float_as_uint(r8A) >> 31) ? 1.f : 0.f;
      const float p0B = (__float_as_uint(r0B) >> 31) ? 1.f : 0.f;
      const float p8B = (__float_as_uint(r8B) >> 31) ? 1.f : 0.f;
      const v2f mm0A = mkv2(m0A, m0A), mm8A = mkv2(m8A, m8A);
      const v2f mm0B = mkv2(m0B, m0B), mm8B = mkv2(m8B, m8B);
      const v2f pp0A = mkv2(p0A, p0A), pp8A = mkv2(p8A, p8A);
      const v2f pp0B = mkv2(p0B, p0B), pp8B = mkv2(p8B, p8B);
      const float4* rv0 = reinterpret_cast<const float4*>(&PWl[(c * NF_ + 0) * SPW]);
      const float4* rv8 = reinterpret_cast<const float4*>(&PWl[(c * NF_ + 8) * SPW]);
      #pragma unroll
      for (int q = 0; q < 4; q++) {
        const float4 a0 = rv0[q], c0 = rv0[q + 4];   // one weight read serves A and B
        const float4 a8 = rv8[q], c8 = rv8[q + 4];
        pkfma(paccA[2*q],   mm0A, lo2(a0));  pkfma(paccA[2*q],   pp0A, lo2(c0));
        pkfma(paccA[2*q+1], mm0A, hi2(a0));  pkfma(paccA[2*q+1], pp0A, hi2(c0));
        pkfma(paccA[2*q],   mm8A, lo2(a8));  pkfma(paccA[2*q],   pp8A, lo2(c8));
        pkfma(paccA[2*q+1], mm8A, hi2(a8));  pkfma(paccA[2*q+1], pp8A, hi2(c8));
        pkfma(paccB[2*q],   mm0B, lo2(a0));  pkfma(paccB[2*q],   pp0B, lo2(c0));
        pkfma(paccB[2*q+1], mm0B, hi2(a0));  pkfma(paccB[2*q+1], pp0B, hi2(c0));
        pkfma(paccB[2*q],   mm8B, lo2(a8));  pkfma(paccB[2*q],   pp8B, lo2(c8));
        pkfma(paccB[2*q+1], mm8B, hi2(a8));  pkfma(paccB[2*q+1], pp8B, hi2(c8));
      }
    }

    // n = 1..7: full twiddles, A and B interleaved, weights read once
    #pragma unroll
    for (int n = 1; n < 8; n++) {
      float reA = 0.f, imA = 0.f, reB = 0.f, imB = 0.f;
      #pragma unroll
      for (int k = 0; k < 8; k++) {
        const int t = (n * k) & 15;
        const float cv = COS16[t], sv = -SIN16F[t];
        const float vA = (n & 1) ? boA[k] : aeA[k];
        const float vB = (n & 1) ? boB[k] : aeB[k];
        reA = fmaf(vA, cv, reA); imA = fmaf(vA, sv, imA);
        reB = fmaf(vB, cv, reB); imB = fmaf(vB, sv, imB);
      }
      const float sA = __builtin_amdgcn_sqrtf(fmaf(reA, reA, imA * imA));
      const float sB = __builtin_amdgcn_sqrtf(fmaf(reB, reB, imB * imB));
      const float magA = fast_log1p(sA), magB = fast_log1p(sB);
      const float phA = atan2pi_fast(imA, reA), phB = atan2pi_fast(imB, reB);
      const v2f mmA = mkv2(magA, magA), ppA = mkv2(phA, phA);
      const v2f mmB = mkv2(magB, magB), ppB = mkv2(phB, phB);
      const float4* rmv = reinterpret_cast<const float4*>(&PWl[(c * NF_ + n) * SPW]);
      #pragma unroll
      for (int q = 0; q < 4; q++) {
        const float4 a  = rmv[q];       // mag weights (read once)
        const float4 bb = rmv[q + 4];   // ph weights
        pkfma(paccA[2*q],   mmA, lo2(a));  pkfma(paccA[2*q],   ppA, lo2(bb));
        pkfma(paccA[2*q+1], mmA, hi2(a));  pkfma(paccA[2*q+1], ppA, hi2(bb));
        pkfma(paccB[2*q],   mmB, lo2(a));  pkfma(paccB[2*q],   ppB, lo2(bb));
        pkfma(paccB[2*q+1], mmB, hi2(a));  pkfma(paccB[2*q+1], ppB, hi2(bb));
      }
    }
  }

  // ---- combine pacc across subs (proven shfl_xor butterflies) ----
  float* pfA = reinterpret_cast<float*>(paccA);
  float* pfB = reinterpret_cast<float*>(paccB);
  #pragma unroll
  for (int j = 0; j < MLP_; j++) {
    pfA[j] += __shfl_xor(pfA[j], 16, 64);
    pfA[j] += __shfl_xor(pfA[j], 32, 64);
    pfB[j] += __shfl_xor(pfB[j], 16, 64);
    pfB[j] += __shfl_xor(pfB[j], 32, 64);
  }
  v2f p2A[8], p2B[8];
  #pragma unroll
  for (int q = 0; q < 8; q++) {
    p2A[q] = mkv2(fast_tanh(pfA[2*q]   + proj_b[2*q])   * PI_F,
                  fast_tanh(pfA[2*q+1] + proj_b[2*q+1]) * PI_F);
    p2B[q] = mkv2(fast_tanh(pfB[2*q]   + proj_b[2*q])   * PI_F,
                  fast_tanh(pfB[2*q+1] + proj_b[2*q+1]) * PI_F);
  }

  // ---- MLP tail: 16 rows per sub; weight reads serve both w's ----
  v2f h2aA[16], h2aB[16];
  #pragma unroll
  for (int q = 0; q < 16; q++) { h2aA[q] = mkv2(0.f, 0.f); h2aB[q] = mkv2(0.f, 0.f); }
  #pragma unroll 4
  for (int ii = 0; ii < 16; ii++) {
    const int i = sub + ii * 4;
    const float4* r1 = reinterpret_cast<const float4*>(&W1p[i * S1]);
    v2f accA = mkv2(B1s[i], 0.f), accB = mkv2(B1s[i], 0.f);
    #pragma unroll
    for (int q = 0; q < 4; q++) {
      const float4 a = r1[q];
      pkfma(accA, p2A[2*q],   lo2(a));
      pkfma(accA, p2A[2*q+1], hi2(a));
      pkfma(accB, p2B[2*q],   lo2(a));
      pkfma(accB, p2B[2*q+1], hi2(a));
    }
    const float h1A = fmaxf(accA.x + accA.y, 0.f);
    const float h1B = fmaxf(accB.x + accB.y, 0.f);
    const v2f hhA = mkv2(h1A, h1A), hhB = mkv2(h1B, h1B);
    const float4* r2 = reinterpret_cast<const float4*>(&W2p[i * S2]);
    #pragma unroll
    for (int q = 0; q < 8; q++) {
      const float4 a = r2[q];
      pkfma(h2aA[2*q],   hhA, lo2(a));
      pkfma(h2aA[2*q+1], hhA, hi2(a));
      pkfma(h2aB[2*q],   hhB, lo2(a));
      pkfma(h2aB[2*q+1], hhB, hi2(a));
    }
  }
  // ---- combine h2a across subs ----
  float* hfA = reinterpret_cast<float*>(h2aA);
  float* hfB = reinterpret_cast<float*>(h2aB);
  #pragma unroll
  for (int m = 0; m < H2_; m++) {
    hfA[m] += __shfl_xor(hfA[m], 16, 64);
    hfA[m] += __shfl_xor(hfA[m], 32, 64);
    hfB[m] += __shfl_xor(hfB[m], 16, 64);
    hfB[m] += __shfl_xor(hfB[m], 32, 64);
  }

  // ---- head split across subs: m in [8*sub, 8*sub+8), combine ----
  float oA = 0.f, oB = 0.f;
  #pragma unroll
  for (int t = 0; t < 8; t++) {
    const int m = sub * 8 + t;
    const float bm = b2[m], wm = out_w[m];
    oA = fmaf(fmaxf(hfA[m] + bm, 0.f), wm, oA);
    oB = fmaf(fmaxf(hfB[m] + bm, 0.f), wm, oB);
  }
  oA += __shfl_xor(oA, 16, 64);
  oA += __shfl_xor(oA, 32, 64);
  oA += out_b[0];
  oB += __shfl_xor(oB, 16, 64);
  oB += __shfl_xor(oB, 32, 64);
  oB += out_b[0];

  float val = 0.f;
  if (sub == 0) {
    val = oA * wts[wA];
    if (wB < W_) val = fmaf(oB, wts[wB], val);
  }
  // reduce the 16 sub0 lanes (bits 0-3); other lanes mix garbage among themselves only
  #pragma unroll
  for (int s = 1; s < 16; s <<= 1) val += __shfl_xor(val, s, 64);
  if (lane == 0) partials[(b * NCHK_ + chunk) * 4 + wave] = val;
}

// ---------------- finalize: one wave per b, fixed-order butterfly over 64 partials ----------------
__global__ __launch_bounds__(64) void finalize_kernel(const float* __restrict__ partials,
                                                      float* __restrict__ out) {
  const int b = blockIdx.x;
  const int l = threadIdx.x;
  float s = partials[b * NCHK_ * 4 + l];   // NCHK_*4 = 64 values
  #pragma unroll
  for (int d = 1; d < 64; d <<= 1) s += __shfl_xor(s, d, 64);
  if (l == 0) out[b] = s;
}

extern "C" void kernel_launch(void* const* d_in, const int* in_sizes, int n_in,
                              void* d_out, int out_size, void* d_ws, size_t ws_size,
                              hipStream_t stream) {
  const float* x      = (const float*)d_in[0];
  const float* proj_w = (const float*)d_in[1];
  const float* proj_b = (const float*)d_in[2];
  const float* w1     = (const float*)d_in[3];
  const float* b1     = (const float*)d_in[4];
  const float* w2     = (const float*)d_in[5];
  const float* b2     = (const float*)d_in[6];
  const float* out_w  = (const float*)d_in[7];
  const float* out_b  = (const float*)d_in[8];
  const float* agg_w  = (const float*)d_in[9];

  float* wts      = (float*)d_ws;                    // 2048 floats
  float* PWt      = (float*)d_ws + 2048;             // 2304 floats
  float* W2t      = (float*)d_ws + 2048 + 2304;      // 2048 floats
  float* partials = (float*)d_ws + 8192;             // B_*NCHK_*4 = 4096 floats

  setup_kernel<<<10, 256, 0, stream>>>(agg_w, wts, proj_w, w2, PWt, W2t);
  tcn_fused<<<dim3(NCHK_, B_), 256, 0, stream>>>(x, PWt, proj_b, w1, b1, W2t, b2,
                                                 out_w, out_b, wts, partials);
  finalize_kernel<<<B_, 64, 0, stream>>>(partials, (float*)d_out);
}